// Round 2
// baseline (347.104 us; speedup 1.0000x reference)
//
#include <hip/hip_runtime.h>

// FullAttention fused block on gfx950. All harness I/O is fp32 (reference
// dtypes); internal compute uses bf16 MFMA with fp32 accumulation.
//
// Pipeline:
//   k_cvt     : w_qkv, w_out fp32 -> bf16
//   k_rmsnorm : x[C][N] fp32 -> xn[C][N] fp32 (residual) + xnT[N][C] bf16
//   k_qkv     : qkv[o][p] = w_qkv[o][c] @ xn[c][p]   (M=1536,K=256,N=4096) bf16
//   k_attn    : flash attention per head, Ows[head][p][d] bf16
//   k_oproj   : out[c][p] = w_out @ Ows + b_out + xn   (fp32 out)
//
// MFMA 16x16x32 bf16 layouts (HW-verified per guide):
//   A-frag: lane holds A[m=lane&15][k=quad*8+j], j=0..7  (8 consecutive k)
//   B-frag: lane holds B[k=quad*8+j][n=lane&15]          (8 consecutive k)
//   C/D   : lane holds D[row=quad*4+reg][col=lane&15], reg=0..3

#define NPIX 4096   // H*W
#define CIN 256
#define INNER 512   // HEADS*DIM_HEAD
#define NHEAD 8
#define DH 64

typedef __bf16 bf16;
typedef __attribute__((ext_vector_type(8))) __bf16 bf16x8;
typedef __attribute__((ext_vector_type(4))) float f32x4;

static __device__ __forceinline__ f32x4 mfma_bf16(bf16x8 a, bf16x8 b, f32x4 c) {
  return __builtin_amdgcn_mfma_f32_16x16x32_bf16(a, b, c, 0, 0, 0);
}

// ---------------- K0: fp32 -> bf16 weight conversion ----------------
__global__ __launch_bounds__(256) void k_cvt(const float* __restrict__ a,
                                             bf16* __restrict__ b, int n) {
  int i = blockIdx.x * 256 + threadIdx.x;
  if (i < n) b[i] = (bf16)a[i];
}

// ---------------- K1: RMSNorm over channels ----------------
__global__ __launch_bounds__(256) void k_rmsnorm(const float* __restrict__ x,
                                                 const float* __restrict__ w,
                                                 float* __restrict__ xn,
                                                 bf16* __restrict__ xnT) {
  int p = blockIdx.x * 256 + threadIdx.x;  // pixel index, coalesced over c-loop
  float ss = 0.f;
  for (int c = 0; c < CIN; ++c) {
    float v = x[c * NPIX + p];
    ss += v * v;
  }
  // xn = x / max(||x||_2, 1e-12) * w[c] * sqrt(C);  sqrt(256)=16
  float inv = 16.0f / fmaxf(sqrtf(ss), 1e-12f);
  for (int c = 0; c < CIN; ++c) {
    float v = x[c * NPIX + p] * inv * w[c];
    xn[c * NPIX + p] = v;
    xnT[p * CIN + c] = (bf16)v;
  }
}

// ---------------- K2: QKV projection GEMM ----------------
// C[o][p] = sum_c w_qkv[o][c] * xn[c][p]
// A = wqkv_bf [1536][256] row-major; B[k=c][n=p] = xnT[p][c] (8 consecutive c/lane)
__global__ __launch_bounds__(256) void k_qkv(const bf16* __restrict__ wqkv,
                                             const bf16* __restrict__ xnT,
                                             bf16* __restrict__ qkv) {
  const int lane = threadIdx.x & 63;
  const int wave = threadIdx.x >> 6;
  const int l15 = lane & 15, quad = lane >> 4;
  const int obase = blockIdx.y * 64 + wave * 16;
  const int pbase = blockIdx.x * 16;
  f32x4 acc = {0.f, 0.f, 0.f, 0.f};
  const bf16* arow = wqkv + (size_t)(obase + l15) * CIN + quad * 8;
  const bf16* brow = xnT + (size_t)(pbase + l15) * CIN + quad * 8;
#pragma unroll
  for (int kc = 0; kc < CIN / 32; ++kc) {
    bf16x8 af = *(const bf16x8*)(arow + kc * 32);
    bf16x8 bfr = *(const bf16x8*)(brow + kc * 32);
    acc = mfma_bf16(af, bfr, acc);
  }
#pragma unroll
  for (int r = 0; r < 4; ++r)
    qkv[(size_t)(obase + quad * 4 + r) * NPIX + pbase + l15] = (bf16)acc[r];
}

// ---------------- K3: flash attention ----------------
// qkv layout [o][p]: q rows 0..511, k rows 512..1023, v rows 1024..1535;
// within a section row = head*64 + d. One block = (head, 64 q-rows); wave = 16 q-rows.
__global__ __launch_bounds__(256) void k_attn(const bf16* __restrict__ qkv,
                                              bf16* __restrict__ Ows) {
  const int head = blockIdx.y;
  const int tid = threadIdx.x;
  const int wave = tid >> 6, lane = tid & 63;
  const int l15 = lane & 15, quad = lane >> 4;

  __shared__ bf16 Klds[32 * 80];      // [key_rel][d], stride 80 (16B-aligned rows)
  __shared__ bf16 Plds[4][16 * 32];   // wave-private P tile [qrow][key_rel]

  const int qo = head * DH;                 // q section base row
  const int ko = INNER + head * DH;         // k section base row
  const int vo = 2 * INNER + head * DH;     // v section base row
  const int qrow = blockIdx.x * 64 + wave * 16;

  // Q fragments (A layout), loaded once: Q[p][d] = qkv[qo+d][p]
  bf16x8 qf[2];
#pragma unroll
  for (int kc = 0; kc < 2; ++kc)
#pragma unroll
    for (int j = 0; j < 8; ++j)
      qf[kc][j] = qkv[(size_t)(qo + kc * 32 + quad * 8 + j) * NPIX + qrow + l15];

  f32x4 o[4];
  float m_r[4], l_r[4];
#pragma unroll
  for (int r = 0; r < 4; ++r) {
    o[0][r] = o[1][r] = o[2][r] = o[3][r] = 0.f;
    m_r[r] = -INFINITY;
    l_r[r] = 0.f;
  }

  for (int kb = 0; kb < NPIX; kb += 32) {
    __syncthreads();
    // stage K tile: Klds[key_rel][d] <- qkv[ko+d][kb+key_rel]
    {
      int d = tid >> 2, kc4 = tid & 3;
      bf16x8 kvec = *(const bf16x8*)(qkv + (size_t)(ko + d) * NPIX + kb + kc4 * 8);
#pragma unroll
      for (int j = 0; j < 8; ++j) Klds[(kc4 * 8 + j) * 80 + d] = kvec[j];
    }
    __syncthreads();

    // S[16 q][32 keys] = Q @ K^T ; B[k=d][n=key] = Klds[key][d]
    f32x4 s[2];
#pragma unroll
    for (int r = 0; r < 4; ++r) { s[0][r] = 0.f; s[1][r] = 0.f; }
#pragma unroll
    for (int nc = 0; nc < 2; ++nc)
#pragma unroll
      for (int kc = 0; kc < 2; ++kc) {
        bf16x8 kf = *(const bf16x8*)(&Klds[(nc * 16 + l15) * 80 + kc * 32 + quad * 8]);
        s[nc] = mfma_bf16(qf[kc], kf, s[nc]);
      }

    // online softmax; row = quad*4+r, cols spread over 16 lanes of the quad
    float p0[4], p1[4], alpha[4];
#pragma unroll
    for (int r = 0; r < 4; ++r) {
      float a = s[0][r] * 0.125f;  // scale = DH^-0.5
      float b = s[1][r] * 0.125f;
      float v = fmaxf(a, b);
      v = fmaxf(v, __shfl_xor(v, 1));
      v = fmaxf(v, __shfl_xor(v, 2));
      v = fmaxf(v, __shfl_xor(v, 4));
      v = fmaxf(v, __shfl_xor(v, 8));
      float mn = fmaxf(m_r[r], v);
      alpha[r] = __expf(m_r[r] - mn);  // exp(-inf)=0 on first tile
      m_r[r] = mn;
      p0[r] = __expf(a - mn);
      p1[r] = __expf(b - mn);
      float sm = p0[r] + p1[r];
      sm += __shfl_xor(sm, 1);
      sm += __shfl_xor(sm, 2);
      sm += __shfl_xor(sm, 4);
      sm += __shfl_xor(sm, 8);
      l_r[r] = l_r[r] * alpha[r] + sm;
    }
#pragma unroll
    for (int c = 0; c < 4; ++c)
#pragma unroll
      for (int r = 0; r < 4; ++r) o[c][r] *= alpha[r];

    // P: C-layout -> LDS -> A-layout (wave-private; in-order LDS per wave)
    bf16* pl = Plds[wave];
#pragma unroll
    for (int r = 0; r < 4; ++r) {
      pl[(quad * 4 + r) * 32 + l15] = (bf16)p0[r];
      pl[(quad * 4 + r) * 32 + 16 + l15] = (bf16)p1[r];
    }
    bf16x8 pf = *(const bf16x8*)(&pl[l15 * 32 + quad * 8]);

    // O += P @ V ; B[k=key][n=d] = V[kb+key][d] = qkv[vo+d][kb+key]
#pragma unroll
    for (int c = 0; c < 4; ++c) {
      bf16x8 vf = *(const bf16x8*)(qkv + (size_t)(vo + c * 16 + l15) * NPIX + kb + quad * 8);
      o[c] = mfma_bf16(pf, vf, o[c]);
    }
  }

#pragma unroll
  for (int r = 0; r < 4; ++r) l_r[r] = 1.0f / l_r[r];
#pragma unroll
  for (int c = 0; c < 4; ++c)
#pragma unroll
    for (int r = 0; r < 4; ++r)
      Ows[((size_t)head * NPIX + qrow + quad * 4 + r) * DH + c * 16 + l15] =
          (bf16)(o[c][r] * l_r[r]);
}

// ---------------- K4: output projection + bias + residual ----------------
// y[c][p] = sum_i w_out[c][i] * AO[i][p] + b_out[c] + xn[c][p],
// AO[i][p] = Ows[(i>>6)*4096 + p][i&63]  (8 consecutive d per lane)
__global__ __launch_bounds__(256) void k_oproj(const bf16* __restrict__ wout,
                                               const bf16* __restrict__ Ows,
                                               const float* __restrict__ bout,
                                               const float* __restrict__ xn,
                                               float* __restrict__ out) {
  const int lane = threadIdx.x & 63, wave = threadIdx.x >> 6;
  const int l15 = lane & 15, quad = lane >> 4;
  const int mbase = blockIdx.y * 64 + wave * 16;
  const int pbase = blockIdx.x * 16;
  f32x4 acc = {0.f, 0.f, 0.f, 0.f};
#pragma unroll
  for (int kc = 0; kc < INNER / 32; ++kc) {
    bf16x8 af = *(const bf16x8*)(wout + (size_t)(mbase + l15) * INNER + kc * 32 + quad * 8);
    int i0 = kc * 32 + quad * 8;           // i0..i0+7 stay within one head
    int head = i0 >> 6, d0 = i0 & 63;
    bf16x8 bfr = *(const bf16x8*)(Ows + ((size_t)head * NPIX + pbase + l15) * DH + d0);
    acc = mfma_bf16(af, bfr, acc);
  }
#pragma unroll
  for (int r = 0; r < 4; ++r) {
    int c = mbase + quad * 4 + r, p = pbase + l15;
    out[c * NPIX + p] = acc[r] + bout[c] + xn[c * NPIX + p];
  }
}

extern "C" void kernel_launch(void* const* d_in, const int* in_sizes, int n_in,
                              void* d_out, int out_size, void* d_ws, size_t ws_size,
                              hipStream_t stream) {
  (void)in_sizes; (void)n_in; (void)out_size; (void)ws_size;
  const float* x      = (const float*)d_in[0];
  const float* norm_w = (const float*)d_in[1];
  const float* w_qkv  = (const float*)d_in[2];
  const float* w_out  = (const float*)d_in[3];
  const float* b_out  = (const float*)d_in[4];
  float* out = (float*)d_out;

  char* ws = (char*)d_ws;
  float* xn    = (float*)(ws);                        // 256*4096*4  = 4 MB
  bf16* xnT    = (bf16*)(ws + (4u << 20));            // 4096*256*2  = 2 MB
  bf16* qkv    = (bf16*)(ws + (6u << 20));            // 1536*4096*2 = 12 MB
  bf16* Ows    = (bf16*)(ws + (18u << 20));           // 8*4096*64*2 = 4 MB
  bf16* wqkv_b = (bf16*)(ws + (22u << 20));           // 1536*256*2  = 0.75 MB
  bf16* wout_b = (bf16*)(ws + (23u << 20));           // 256*512*2   = 0.25 MB

  hipLaunchKernelGGL(k_cvt, dim3((3 * INNER * CIN + 255) / 256), dim3(256), 0, stream,
                     w_qkv, wqkv_b, 3 * INNER * CIN);
  hipLaunchKernelGGL(k_cvt, dim3((CIN * INNER + 255) / 256), dim3(256), 0, stream,
                     w_out, wout_b, CIN * INNER);
  hipLaunchKernelGGL(k_rmsnorm, dim3(16), dim3(256), 0, stream, x, norm_w, xn, xnT);
  hipLaunchKernelGGL(k_qkv, dim3(NPIX / 16, 1536 / 64), dim3(256), 0, stream,
                     wqkv_b, xnT, qkv);
  hipLaunchKernelGGL(k_attn, dim3(NPIX / 64, NHEAD), dim3(256), 0, stream, qkv, Ows);
  hipLaunchKernelGGL(k_oproj, dim3(NPIX / 16, CIN / 64), dim3(256), 0, stream,
                     wout_b, Ows, b_out, xn, out);
}